// Round 1
// baseline (295.277 us; speedup 1.0000x reference)
//
#include <hip/hip_runtime.h>
#include <math.h>

// Cross-bilateral filter, B=4, C=3, H=720, W=1280, WIN=11 (pad=5), f32.
// out[b,c,y,x] = sum_{dy,dx} w * inp[b,c,cy,cx] / sum w
//   w = exp(-(|dAlb|^2/0.01 + |dNrm|^2/0.1 + dDep^2/0.1))
//   cy = clamp(y+dy-5, 0, H-1), cx = clamp(x+dx-5, 0, W-1)   (edge padding)
//
// Strategy: LDS tile (16x32 outputs + 5 halo = 26x42) holding three float4
// planes: {albedo.rgb, depth} and {normal.rgb, 0} PRE-SCALED by
// sqrt(log2(e)/sigma) so the tap weight is exp2(-sum d^2) -> single
// v_exp_f32 with free neg modifier. Third plane = raw input.rgb.
// 2 output pixels per thread (rows ly, ly+8). dx unrolled x11.

#define HH   720
#define WW   1280
#define PAD  5
#define WIN  11
#define TW   32
#define TH   16
#define HALO_W (TW + 2 * PAD)   // 42
#define HALO_H (TH + 2 * PAD)   // 26

__global__ __launch_bounds__(256, 3)
void xbilateral_kernel(const float* __restrict__ inp,
                       const float* __restrict__ alb,
                       const float* __restrict__ nrm,
                       const float* __restrict__ dep,
                       float* __restrict__ out)
{
    __shared__ float4 sG[HALO_H][HALO_W];   // scaled albedo rgb + scaled depth
    __shared__ float4 sN[HALO_H][HALO_W];   // scaled normal rgb + 0
    __shared__ float4 sI[HALO_H][HALO_W];   // input rgb + 0

    const int tid = threadIdx.x;
    const int lx  = tid & 31;       // 0..31
    const int ly  = tid >> 5;       // 0..7
    const int bx0 = blockIdx.x * TW;
    const int by0 = blockIdx.y * TH;
    const int b   = blockIdx.z;

    // sqrt(log2(e)/sigma): log2(e)=1.4426950408889634
    const float kA = 12.01122406f;  // sqrt(1.44269504/0.01)
    const float kN = 3.79828255f;   // sqrt(1.44269504/0.1)  (also depth)

    const size_t plane = (size_t)HH * WW;
    const float* albB = alb + (size_t)b * 3 * plane;
    const float* nrmB = nrm + (size_t)b * 3 * plane;
    const float* inpB = inp + (size_t)b * 3 * plane;
    const float* depB = dep + (size_t)b * plane;

    // ---- stage halo tile into LDS (clamped coords, pre-scaled) ----
    for (int idx = tid; idx < HALO_H * HALO_W; idx += 256) {
        int r = idx / HALO_W;
        int c = idx - r * HALO_W;
        int gy = by0 + r - PAD; gy = min(max(gy, 0), HH - 1);
        int gx = bx0 + c - PAD; gx = min(max(gx, 0), WW - 1);
        size_t o = (size_t)gy * WW + gx;
        float a0 = albB[o], a1 = albB[plane + o], a2 = albB[2 * plane + o];
        float n0 = nrmB[o], n1 = nrmB[plane + o], n2 = nrmB[2 * plane + o];
        float i0 = inpB[o], i1 = inpB[plane + o], i2 = inpB[2 * plane + o];
        float d0 = depB[o];
        sG[r][c] = make_float4(a0 * kA, a1 * kA, a2 * kA, d0 * kN);
        sN[r][c] = make_float4(n0 * kN, n1 * kN, n2 * kN, 0.f);
        sI[r][c] = make_float4(i0, i1, i2, 0.f);
    }
    __syncthreads();

    // ---- per-thread: two output pixels, rows ly and ly+8 ----
    const float4 cG_A = sG[ly + PAD][lx + PAD];
    const float4 cN_A = sN[ly + PAD][lx + PAD];
    const float4 cG_B = sG[ly + 8 + PAD][lx + PAD];
    const float4 cN_B = sN[ly + 8 + PAD][lx + PAD];

    float4 accA = make_float4(0.f, 0.f, 0.f, 0.f);  // rgb acc + wsum
    float4 accB = make_float4(0.f, 0.f, 0.f, 0.f);

    for (int dy = 0; dy < WIN; ++dy) {
        const float4* rG_A = &sG[ly + dy][lx];
        const float4* rN_A = &sN[ly + dy][lx];
        const float4* rI_A = &sI[ly + dy][lx];
        const float4* rG_B = &sG[ly + 8 + dy][lx];
        const float4* rN_B = &sN[ly + 8 + dy][lx];
        const float4* rI_B = &sI[ly + 8 + dy][lx];
#pragma unroll
        for (int dx = 0; dx < WIN; ++dx) {
            {
                float4 g = rG_A[dx], n = rN_A[dx], i = rI_A[dx];
                float d = g.x - cG_A.x; float e = d * d;
                d = g.y - cG_A.y; e = fmaf(d, d, e);
                d = g.z - cG_A.z; e = fmaf(d, d, e);
                d = g.w - cG_A.w; e = fmaf(d, d, e);
                d = n.x - cN_A.x; e = fmaf(d, d, e);
                d = n.y - cN_A.y; e = fmaf(d, d, e);
                d = n.z - cN_A.z; e = fmaf(d, d, e);
                float wg = __builtin_amdgcn_exp2f(-e);
                accA.x = fmaf(wg, i.x, accA.x);
                accA.y = fmaf(wg, i.y, accA.y);
                accA.z = fmaf(wg, i.z, accA.z);
                accA.w += wg;
            }
            {
                float4 g = rG_B[dx], n = rN_B[dx], i = rI_B[dx];
                float d = g.x - cG_B.x; float e = d * d;
                d = g.y - cG_B.y; e = fmaf(d, d, e);
                d = g.z - cG_B.z; e = fmaf(d, d, e);
                d = g.w - cG_B.w; e = fmaf(d, d, e);
                d = n.x - cN_B.x; e = fmaf(d, d, e);
                d = n.y - cN_B.y; e = fmaf(d, d, e);
                d = n.z - cN_B.z; e = fmaf(d, d, e);
                float wg = __builtin_amdgcn_exp2f(-e);
                accB.x = fmaf(wg, i.x, accB.x);
                accB.y = fmaf(wg, i.y, accB.y);
                accB.z = fmaf(wg, i.z, accB.z);
                accB.w += wg;
            }
        }
    }

    // ---- write out ----
    const int ox  = bx0 + lx;
    const int oyA = by0 + ly;
    const int oyB = oyA + 8;
    float* outB = out + (size_t)b * 3 * plane;
    float invA = 1.0f / fmaxf(accA.w, 1e-10f);
    float invB = 1.0f / fmaxf(accB.w, 1e-10f);
    size_t oA = (size_t)oyA * WW + ox;
    size_t oB = (size_t)oyB * WW + ox;
    outB[oA]             = accA.x * invA;
    outB[plane + oA]     = accA.y * invA;
    outB[2 * plane + oA] = accA.z * invA;
    outB[oB]             = accB.x * invB;
    outB[plane + oB]     = accB.y * invB;
    outB[2 * plane + oB] = accB.z * invB;
}

extern "C" void kernel_launch(void* const* d_in, const int* in_sizes, int n_in,
                              void* d_out, int out_size, void* d_ws, size_t ws_size,
                              hipStream_t stream) {
    const float* inp = (const float*)d_in[0];
    const float* alb = (const float*)d_in[1];
    const float* nrm = (const float*)d_in[2];
    const float* dep = (const float*)d_in[3];
    // d_in[4] = win_size (always 11, compiled in)
    float* out = (float*)d_out;

    dim3 grid(WW / TW, HH / TH, 4);   // 40 x 45 x 4
    dim3 block(256);
    xbilateral_kernel<<<grid, block, 0, stream>>>(inp, alb, nrm, dep, out);
}

// Round 3
// 214.918 us; speedup vs baseline: 1.3739x; 1.3739x over previous
//
#include <hip/hip_runtime.h>
#include <math.h>

// Cross-bilateral filter, B=4, C=3, H=720, W=1280, WIN=11 (pad=5), f32.
//
// R3 = R2 design with the cvt_pkrtz type fixed (bit_cast __fp16v2 -> _Float16v2).
//  - Guides (albedo rgb, depth, normal rgb) pre-scaled by sqrt(log2e/sigma)
//    and packed as 8 x f16 in ONE uint4 LDS cell -> one ds_read_b128 per tap
//    (was two). Weight = exp2(-sum d^2), d in packed f16, accumulated in f32
//    via v_dot2_f32_f16.
//  - Two VERTICALLY ADJACENT pixels per thread (rows 2ly, 2ly+1): LDS cell
//    [2ly+wy][lx+dx] serves pixel A (dy=wy) and pixel B (dy=wy-1) -> each
//    cell read once for two tap-uses. 12 row-reads serve 22 row-uses.
//  - LDS 34.9 KB -> 4 blocks/CU (16 waves/CU, 50% occupancy).

#define HH   720
#define WW   1280
#define PAD  5
#define WIN  11
#define TW   32
#define TH   16
#define HALO_W (TW + 2 * PAD)   // 42
#define HALO_H (TH + 2 * PAD)   // 26

typedef _Float16 h2 __attribute__((ext_vector_type(2)));

__device__ __forceinline__ unsigned int pkh2(float a, float b) {
    return __builtin_bit_cast(unsigned int, __builtin_amdgcn_cvt_pkrtz(a, b));
}

__device__ __forceinline__ float dot2acc(h2 d, float acc) {
#if __has_builtin(__builtin_amdgcn_fdot2)
    return __builtin_amdgcn_fdot2(d, d, acc, false);
#else
    float x = (float)d.x, y = (float)d.y;
    return fmaf(x, x, fmaf(y, y, acc));
#endif
}

struct C8 { h2 c0, c1, c2, c3; };

__device__ __forceinline__ C8 unpackC(uint4 g) {
    C8 c;
    c.c0 = __builtin_bit_cast(h2, g.x);
    c.c1 = __builtin_bit_cast(h2, g.y);
    c.c2 = __builtin_bit_cast(h2, g.z);
    c.c3 = __builtin_bit_cast(h2, g.w);
    return c;
}

__device__ __forceinline__ void tap(const C8& c, uint4 g, float4 iv, float4& acc) {
    h2 d0 = __builtin_bit_cast(h2, g.x) - c.c0;
    h2 d1 = __builtin_bit_cast(h2, g.y) - c.c1;
    h2 d2 = __builtin_bit_cast(h2, g.z) - c.c2;
    h2 d3 = __builtin_bit_cast(h2, g.w) - c.c3;
    float e = dot2acc(d0, dot2acc(d1, dot2acc(d2, dot2acc(d3, 0.f))));
    float w = __builtin_amdgcn_exp2f(-e);
    acc.x = fmaf(w, iv.x, acc.x);
    acc.y = fmaf(w, iv.y, acc.y);
    acc.z = fmaf(w, iv.z, acc.z);
    acc.w += w;
}

__global__ __launch_bounds__(256, 4)
void xbilateral_kernel(const float* __restrict__ inp,
                       const float* __restrict__ alb,
                       const float* __restrict__ nrm,
                       const float* __restrict__ dep,
                       float* __restrict__ out)
{
    __shared__ uint4  sG[HALO_H][HALO_W];   // 8 x f16: scaled {a0,a1,a2,dep,n0,n1,n2,0}
    __shared__ float4 sI[HALO_H][HALO_W];   // input rgb + pad

    const int tid = threadIdx.x;
    const int lx  = tid & 31;       // 0..31
    const int ly  = tid >> 5;       // 0..7
    const int bx0 = blockIdx.x * TW;
    const int by0 = blockIdx.y * TH;
    const int b   = blockIdx.z;

    // sqrt(log2(e)/sigma): log2(e)=1.4426950408889634
    const float kA = 12.01122406f;  // sqrt(1.44269504/0.01)
    const float kN = 3.79828255f;   // sqrt(1.44269504/0.1)  (also depth)

    const size_t plane = (size_t)HH * WW;
    const float* albB = alb + (size_t)b * 3 * plane;
    const float* nrmB = nrm + (size_t)b * 3 * plane;
    const float* inpB = inp + (size_t)b * 3 * plane;
    const float* depB = dep + (size_t)b * plane;

    // ---- stage halo tile into LDS (clamped coords, pre-scaled, f16-packed) ----
    for (int idx = tid; idx < HALO_H * HALO_W; idx += 256) {
        int r = idx / HALO_W;
        int c = idx - r * HALO_W;
        int gy = by0 + r - PAD; gy = min(max(gy, 0), HH - 1);
        int gx = bx0 + c - PAD; gx = min(max(gx, 0), WW - 1);
        size_t o = (size_t)gy * WW + gx;
        float a0 = albB[o], a1 = albB[plane + o], a2 = albB[2 * plane + o];
        float n0 = nrmB[o], n1 = nrmB[plane + o], n2 = nrmB[2 * plane + o];
        float i0 = inpB[o], i1 = inpB[plane + o], i2 = inpB[2 * plane + o];
        float d0 = depB[o];
        sG[r][c] = make_uint4(pkh2(a0 * kA, a1 * kA),
                              pkh2(a2 * kA, d0 * kN),
                              pkh2(n0 * kN, n1 * kN),
                              pkh2(n2 * kN, 0.f));
        sI[r][c] = make_float4(i0, i1, i2, 0.f);
    }
    __syncthreads();

    // ---- per-thread: two vertically adjacent pixels, tile rows 2ly, 2ly+1 ----
    const int pyA = 2 * ly;              // tile row of pixel A
    const C8 cA = unpackC(sG[pyA + PAD][lx + PAD]);
    const C8 cB = unpackC(sG[pyA + 1 + PAD][lx + PAD]);

    float4 accA = make_float4(0.f, 0.f, 0.f, 0.f);  // rgb acc + wsum
    float4 accB = make_float4(0.f, 0.f, 0.f, 0.f);

    // wy = 0: pixel A only (dyA = 0)
    {
        const uint4*  rg = &sG[pyA][lx];
        const float4* ri = &sI[pyA][lx];
#pragma unroll
        for (int dx = 0; dx < WIN; ++dx)
            tap(cA, rg[dx], ri[dx], accA);
    }
    // wy = 1..10: both pixels (dyA = wy, dyB = wy-1) share the same cells
    for (int wy = 1; wy <= 10; ++wy) {
        const uint4*  rg = &sG[pyA + wy][lx];
        const float4* ri = &sI[pyA + wy][lx];
#pragma unroll
        for (int dx = 0; dx < WIN; ++dx) {
            uint4  g  = rg[dx];
            float4 iv = ri[dx];
            tap(cA, g, iv, accA);
            tap(cB, g, iv, accB);
        }
    }
    // wy = 11: pixel B only (dyB = 10)
    {
        const uint4*  rg = &sG[pyA + 11][lx];
        const float4* ri = &sI[pyA + 11][lx];
#pragma unroll
        for (int dx = 0; dx < WIN; ++dx)
            tap(cB, rg[dx], ri[dx], accB);
    }

    // ---- write out ----
    const int ox  = bx0 + lx;
    const int oyA = by0 + pyA;
    const int oyB = oyA + 1;
    float* outB = out + (size_t)b * 3 * plane;
    float invA = 1.0f / fmaxf(accA.w, 1e-10f);
    float invB = 1.0f / fmaxf(accB.w, 1e-10f);
    size_t oA = (size_t)oyA * WW + ox;
    size_t oB = (size_t)oyB * WW + ox;
    outB[oA]             = accA.x * invA;
    outB[plane + oA]     = accA.y * invA;
    outB[2 * plane + oA] = accA.z * invA;
    outB[oB]             = accB.x * invB;
    outB[plane + oB]     = accB.y * invB;
    outB[2 * plane + oB] = accB.z * invB;
}

extern "C" void kernel_launch(void* const* d_in, const int* in_sizes, int n_in,
                              void* d_out, int out_size, void* d_ws, size_t ws_size,
                              hipStream_t stream) {
    const float* inp = (const float*)d_in[0];
    const float* alb = (const float*)d_in[1];
    const float* nrm = (const float*)d_in[2];
    const float* dep = (const float*)d_in[3];
    // d_in[4] = win_size (always 11, compiled in)
    float* out = (float*)d_out;

    dim3 grid(WW / TW, HH / TH, 4);   // 40 x 45 x 4
    dim3 block(256);
    xbilateral_kernel<<<grid, block, 0, stream>>>(inp, alb, nrm, dep, out);
}